// Round 1
// baseline (3424.128 us; speedup 1.0000x reference)
//
#include <hip/hip_runtime.h>
#include <cstdint>

#define N_NODES 50000
#define N_EDGES 800000
#define DIM 128
#define KSEL 5000
#define MCONST (2 * N_EDGES + 2)   // 1600002

typedef unsigned long long u64;
typedef uint32_t u32;

// ---------------- GEMM: Y[row, t] = sum_k X[row,k] * W[k,t] ----------------
// grid = nrows, block = 128
__global__ void gemm128(const float* __restrict__ X, const float* __restrict__ W,
                        float* __restrict__ Y) {
  int row = blockIdx.x;
  int t = threadIdx.x;
  __shared__ float xs[DIM];
  xs[t] = X[row * DIM + t];
  __syncthreads();
  float acc = 0.f;
#pragma unroll 16
  for (int k = 0; k < DIM; k++) acc = fmaf(xs[k], W[k * DIM + t], acc);
  Y[row * DIM + t] = acc;
}

// ---------------- degree counts ----------------
__global__ void deg_kernel(const int* __restrict__ row, const int* __restrict__ col,
                           int* deg1, int* deg2) {
  int e = blockIdx.x * blockDim.x + threadIdx.x;
  if (e < N_EDGES) {
    atomicAdd(&deg1[col[e]], 1);   // in-degree at col (GCN norm)
    atomicAdd(&deg2[row[e]], 1);   // bincount(row) (topk-pool degree)
  }
}

// ---------------- GCN1 scatter: agg[col] += norm * h[row] ----------------
__global__ void scatter1(const int* __restrict__ row, const int* __restrict__ col,
                         const int* __restrict__ deg1,
                         const float* __restrict__ h, float* __restrict__ agg) {
  int gid = blockIdx.x * blockDim.x + threadIdx.x;
  int e = gid >> 7, d = gid & 127;
  if (e < N_EDGES) {
    int r = row[e], c = col[e];
    float norm = 1.0f / sqrtf(((float)deg1[r] + 1.f) * ((float)deg1[c] + 1.f));
    atomicAdd(&agg[c * DIM + d], norm * h[r * DIM + d]);
  }
}

// ---------------- combine1: x1 = relu(agg + dinv2*h + b1); raw; key ----------
// grid = N, block = 128.  B holds agg on input, x1 on output (in place).
__global__ void combine1(float* __restrict__ B, const float* __restrict__ h,
                         const int* __restrict__ deg1, const float* __restrict__ b1,
                         const float* __restrict__ wscore,
                         float* __restrict__ raw, u64* __restrict__ key) {
  int i = blockIdx.x, t = threadIdx.x;
  float dinv2 = 1.0f / ((float)deg1[i] + 1.0f);
  float v = B[i * DIM + t] + dinv2 * h[i * DIM + t] + b1[t];
  v = v > 0.f ? v : 0.f;
  B[i * DIM + t] = v;
  __shared__ float red[DIM];
  red[t] = v * wscore[t];
  __syncthreads();
  for (int s = DIM / 2; s > 0; s >>= 1) {
    if (t < s) red[t] += red[t + s];
    __syncthreads();
  }
  if (t == 0) {
    float r = red[0];
    raw[i] = r;
    u32 b = __float_as_uint(r);
    if ((b << 1) == 0u) b = 0u;                       // normalize -0 -> +0
    u32 ord = (b & 0x80000000u) ? ~b : (b | 0x80000000u);  // monotonic in value
    key[i] = (((u64)(~ord)) << 32) | (u32)i;          // asc key = desc value, tie asc idx
  }
}

// ---------------- exact rank: rank[i] = #{j : key[j] < key[i]} ----------------
__global__ void rank_kernel(const u64* __restrict__ key, int* __restrict__ rank) {
  int i = blockIdx.x * blockDim.x + threadIdx.x;
  u64 mykey = (i < N_NODES) ? key[i] : ~0ull;
  __shared__ u64 sk[256];
  int cnt = 0;
  for (int base = 0; base < N_NODES; base += 256) {
    int j = base + threadIdx.x;
    sk[threadIdx.x] = (j < N_NODES) ? key[j] : ~0ull;
    __syncthreads();
    int lim = min(256, N_NODES - base);
#pragma unroll 4
    for (int t = 0; t < lim; t++) cnt += (sk[t] < mykey) ? 1 : 0;
    __syncthreads();
  }
  if (i < N_NODES) rank[i] = cnt;
}

// ---------------- global fallback: kept node with max deg2, tie -> lowest rank --
__global__ void fallback_kernel(const int* __restrict__ rank, const int* __restrict__ deg2,
                                u64* fbkey) {
  int i = blockIdx.x * blockDim.x + threadIdx.x;
  if (i < N_NODES && rank[i] < KSEL) {
    u64 k = (((u64)(deg2[i] + 1)) << 32) | (u32)(KSEL - 1 - rank[i]);
    atomicMax(fbkey, k);
  }
}

// ---------------- best kept neighbor per owner (comp+1, atomicMax) ------------
__global__ void bestneigh_kernel(const int* __restrict__ row, const int* __restrict__ col,
                                 const int* __restrict__ rank, const int* __restrict__ deg2,
                                 u64* __restrict__ best) {
  int e = blockIdx.x * blockDim.x + threadIdx.x;
  if (e < N_EDGES) {
    int r = row[e], c = col[e];
    if (rank[c] < KSEL) {  // entry (owner=r, neigh=c, order=2e)
      u64 comp = (u64)deg2[c] * (u64)MCONST + (u64)(MCONST - 1 - 2 * e);
      atomicMax(&best[r], comp + 1);
    }
    if (rank[r] < KSEL) {  // entry (owner=c, neigh=r, order=2e+1)
      u64 comp = (u64)deg2[r] * (u64)MCONST + (u64)(MCONST - 2 - 2 * e);
      atomicMax(&best[c], comp + 1);
    }
  }
}

// ---------------- cluster assignment + counts ----------------
__global__ void assign_kernel(const int* __restrict__ rank, const u64* __restrict__ best,
                              const int* __restrict__ row, const int* __restrict__ col,
                              const u64* __restrict__ fbkey,
                              int* __restrict__ cluster, int* __restrict__ counts) {
  int i = blockIdx.x * blockDim.x + threadIdx.x;
  if (i >= N_NODES) return;
  int c;
  int rk = rank[i];
  if (rk < KSEL) {
    c = rk;
  } else {
    u64 b = best[i];
    if (b > 0) {
      u64 comp = b - 1;
      int rem = (int)(comp % (u64)MCONST);
      int ord = MCONST - 1 - rem;
      int e = ord >> 1;
      int nb = (ord & 1) ? row[e] : col[e];
      c = rank[nb];
    } else {
      c = KSEL - 1 - (int)((*fbkey) & 0xffffffffu);
    }
  }
  cluster[i] = c;
  atomicAdd(&counts[c], 1);
}

// ---------------- pool sums: sums[cluster[i]] += x1[i] * tanh(raw[i]) ---------
__global__ void pool_kernel(const float* __restrict__ x1, const float* __restrict__ raw,
                            const int* __restrict__ cluster, float* __restrict__ sums) {
  int gid = blockIdx.x * blockDim.x + threadIdx.x;
  int i = gid >> 7, d = gid & 127;
  if (i < N_NODES) {
    float g = tanhf(raw[i]);
    atomicAdd(&sums[cluster[i] * DIM + d], x1[i * DIM + d] * g);
  }
}

// ---------------- x_p = sums / counts (in place) ----------------
__global__ void xp_kernel(float* __restrict__ sums, const int* __restrict__ counts) {
  int gid = blockIdx.x * blockDim.x + threadIdx.x;
  int c = gid >> 7;
  if (c < KSEL) sums[gid] /= (float)max(counts[c], 1);
}

// ---------------- coarse degrees: degc[cv] += (cu != cv) ----------------
__global__ void degc_kernel(const int* __restrict__ row, const int* __restrict__ col,
                            const int* __restrict__ cluster, int* __restrict__ degc) {
  int e = blockIdx.x * blockDim.x + threadIdx.x;
  if (e < N_EDGES) {
    int cu = cluster[row[e]], cv = cluster[col[e]];
    if (cu != cv) atomicAdd(&degc[cv], 1);
  }
}

// ---------------- GCN2 scatter ----------------
__global__ void scatter2(const int* __restrict__ row, const int* __restrict__ col,
                         const int* __restrict__ cluster, const int* __restrict__ degc,
                         const float* __restrict__ h2, float* __restrict__ agg2) {
  int gid = blockIdx.x * blockDim.x + threadIdx.x;
  int e = gid >> 7, d = gid & 127;
  if (e < N_EDGES) {
    int cu = cluster[row[e]], cv = cluster[col[e]];
    if (cu != cv) {
      float norm = 1.0f / sqrtf(((float)degc[cu] + 1.f) * ((float)degc[cv] + 1.f));
      atomicAdd(&agg2[cv * DIM + d], norm * h2[cu * DIM + d]);
    }
  }
}

// ---------------- combine2: xp2 = agg2 + dinv2*h2 + b2 (in place in agg2) -----
__global__ void combine2(float* __restrict__ agg2, const float* __restrict__ h2,
                         const int* __restrict__ degc, const float* __restrict__ b2) {
  int gid = blockIdx.x * blockDim.x + threadIdx.x;
  int c = gid >> 7, d = gid & 127;
  if (c < KSEL) {
    float dinv2 = 1.0f / ((float)degc[c] + 1.0f);
    agg2[gid] = agg2[gid] + dinv2 * h2[gid] + b2[d];
  }
}

// ---------------- final: out = xp2[cluster] + x1 @ W_skip + b_skip ------------
// grid = N, block = 128
__global__ void final_kernel(const float* __restrict__ x1, const float* __restrict__ Wsk,
                             const float* __restrict__ bsk, const float* __restrict__ xp2,
                             const int* __restrict__ cluster, float* __restrict__ out) {
  int i = blockIdx.x, t = threadIdx.x;
  __shared__ float xs[DIM];
  xs[t] = x1[i * DIM + t];
  __syncthreads();
  float acc = 0.f;
#pragma unroll 16
  for (int k = 0; k < DIM; k++) acc = fmaf(xs[k], Wsk[k * DIM + t], acc);
  out[i * DIM + t] = acc + bsk[t] + xp2[cluster[i] * DIM + t];
  if (i == 0 && t == 0) out[(size_t)N_NODES * DIM] = 0.0f;  // tuple's scalar 0.0
}

extern "C" void kernel_launch(void* const* d_in, const int* in_sizes, int n_in,
                              void* d_out, int out_size, void* d_ws, size_t ws_size,
                              hipStream_t stream) {
  const float* x      = (const float*)d_in[0];
  const int*   eidx   = (const int*)d_in[1];
  const float* W1     = (const float*)d_in[2];
  const float* b1     = (const float*)d_in[3];
  const float* W2     = (const float*)d_in[4];
  const float* b2     = (const float*)d_in[5];
  const float* wscore = (const float*)d_in[6];
  const float* Wsk    = (const float*)d_in[7];
  const float* bsk    = (const float*)d_in[8];
  float* out = (float*)d_out;

  const int* row = eidx;
  const int* col = eidx + N_EDGES;

  // ---- workspace carve (all offsets 8-byte aligned) ----
  char* ws = (char*)d_ws;
  size_t off = 0;
  float* h = (float*)(ws + off); off += (size_t)N_NODES * DIM * 4;     // 25,600,000
  // --- zeroed region start ---
  size_t zoff = off;
  float* B     = (float*)(ws + off); off += (size_t)N_NODES * DIM * 4; // agg1 / x1
  int*   deg1  = (int*)(ws + off);   off += (size_t)N_NODES * 4;
  int*   deg2  = (int*)(ws + off);   off += (size_t)N_NODES * 4;
  u64*   best  = (u64*)(ws + off);   off += (size_t)N_NODES * 8;
  float* sums  = (float*)(ws + off); off += (size_t)KSEL * DIM * 4;    // -> x_p
  int*   counts= (int*)(ws + off);   off += (size_t)KSEL * 4;
  float* agg2  = (float*)(ws + off); off += (size_t)KSEL * DIM * 4;    // -> xp2
  int*   degc  = (int*)(ws + off);   off += (size_t)KSEL * 4;
  u64*   fbkey = (u64*)(ws + off);   off += 8;
  size_t zsize = off - zoff;
  // --- zeroed region end ---
  float* raw     = (float*)(ws + off); off += (size_t)N_NODES * 4;
  u64*   key     = (u64*)(ws + off);   off += (size_t)N_NODES * 8;
  int*   rank    = (int*)(ws + off);   off += (size_t)N_NODES * 4;
  int*   cluster = (int*)(ws + off);   off += (size_t)N_NODES * 4;
  float* h2      = (float*)(ws + off); off += (size_t)KSEL * DIM * 4;
  (void)ws_size; (void)out_size; (void)n_in; (void)in_sizes;

  hipMemsetAsync(ws + zoff, 0, zsize, stream);

  const int eb = (N_EDGES + 255) / 256;          // 3125
  const int nb = (N_NODES + 255) / 256;          // 196
  const int edb = (N_EDGES * DIM) / 256;         // 400,000
  const int ndb = (N_NODES * DIM) / 256;         // 25,000
  const int kdb = (KSEL * DIM) / 256;            // 2,500

  // GCN1
  gemm128<<<N_NODES, DIM, 0, stream>>>(x, W1, h);
  deg_kernel<<<eb, 256, 0, stream>>>(row, col, deg1, deg2);
  scatter1<<<edb, 256, 0, stream>>>(row, col, deg1, h, B);
  combine1<<<N_NODES, DIM, 0, stream>>>(B, h, deg1, b1, wscore, raw, key);
  // top-k + clustering
  rank_kernel<<<nb, 256, 0, stream>>>(key, rank);
  fallback_kernel<<<nb, 256, 0, stream>>>(rank, deg2, fbkey);
  bestneigh_kernel<<<eb, 256, 0, stream>>>(row, col, rank, deg2, best);
  assign_kernel<<<nb, 256, 0, stream>>>(rank, best, row, col, fbkey, cluster, counts);
  // mean pool
  pool_kernel<<<ndb, 256, 0, stream>>>(B, raw, cluster, sums);
  xp_kernel<<<kdb, 256, 0, stream>>>(sums, counts);
  // GCN2 on coarse graph
  degc_kernel<<<eb, 256, 0, stream>>>(row, col, cluster, degc);
  gemm128<<<KSEL, DIM, 0, stream>>>(sums, W2, h2);
  scatter2<<<edb, 256, 0, stream>>>(row, col, cluster, degc, h2, agg2);
  combine2<<<kdb, 256, 0, stream>>>(agg2, h2, degc, b2);
  // broadcast + skip
  final_kernel<<<N_NODES, DIM, 0, stream>>>(B, Wsk, bsk, agg2, cluster, out);
}